// Round 1
// baseline (4834.550 us; speedup 1.0000x reference)
//
#include <hip/hip_runtime.h>

typedef unsigned short u16;
typedef unsigned int   u32;
typedef signed char    i8;
typedef __attribute__((ext_vector_type(8))) short  short8;
typedef __attribute__((ext_vector_type(8))) __bf16 bf16x8;
typedef __attribute__((ext_vector_type(4))) float  f32x4;

// ---------------- problem constants ----------------
#define NSTEP 512
#define BATCH 64
#define HID   512
// recurrence decomposition: 4 batch groups x 16 column groups = 64 WGs
#define NBG 4
#define NCG 16

// ---------------- workspace layout (bytes) ----------------
#define OFF_QXBF  0ull
#define SZ_QXBF   (32768ull*512*2)          // x quantized, bf16(int)
#define OFF_QWT   (OFF_QXBF + SZ_QXBF)
#define SZ_QWT    (1536ull*512*2)           // W^T quantized, bf16(int)
#define OFF_QRT   (OFF_QWT + SZ_QWT)        // R^T quantized, bf16(int)
#define OFF_QWX   (OFF_QRT + SZ_QWT)
#define SZ_QWX    (32768ull*1536)           // Wx quantized, int8
#define OFF_QBX   (OFF_QWX + SZ_QWX)        // 1536 int
#define OFF_QBR   (OFF_QBX + 6144)          // 1536 int
#define OFF_LUT   (OFF_QBR + 6144)          // 256 int sigmoid + 256 int tanh
#define OFF_RING  (OFF_LUT + 2048)          // 2 slots x 4 bg x 8192 u16 (h images)
#define SZ_RING   (2ull*4*8192*2)
#define OFF_FLAGS (OFF_RING + SZ_RING)      // 513*4 ints
#define SZ_FLAGS  (2052ull*4)
#define WS_NEED   (OFF_FLAGS + SZ_FLAGS)

// ---------------- helpers ----------------
__device__ __forceinline__ int iclip8(int v){ return v < -128 ? -128 : (v > 127 ? 127 : v); }

// round-half-even of (v / 2^k) for integer v (matches rintf/jnp.round on exact values)
__device__ __forceinline__ int rhe(int v, int k){
  int b = v >> k;                 // floor
  int r = v & ((1 << k) - 1);
  int half = 1 << (k - 1);
  return b + ((r > half) || (r == half && (b & 1)));
}

__device__ __forceinline__ u16 f2bf(float f){ return (u16)(__builtin_bit_cast(u32, f) >> 16); }

// quantize x*s to [-128,127], return exact bf16 of the (integer) result
__device__ __forceinline__ u16 qbf(float x, float s){
  float q = rintf(x * s);
  q = fminf(fmaxf(q, -128.f), 127.f);
  return f2bf(q);   // integers |q|<=128 are exact in bf16
}

// MFMA wrapper: tolerate either short8- or bf16x8-typed builtin signature.
template<typename V>
__device__ __forceinline__ auto mfma_sel(V a, V b, f32x4 c, int)
  -> decltype(__builtin_amdgcn_mfma_f32_16x16x32_bf16(a, b, c, 0, 0, 0)) {
  return __builtin_amdgcn_mfma_f32_16x16x32_bf16(a, b, c, 0, 0, 0);
}
template<typename V>
__device__ __forceinline__ f32x4 mfma_sel(V a, V b, f32x4 c, long) {
  return __builtin_amdgcn_mfma_f32_16x16x32_bf16(
      __builtin_bit_cast(bf16x8, a), __builtin_bit_cast(bf16x8, b), c, 0, 0, 0);
}
__device__ __forceinline__ f32x4 mfma_bf16(short8 a, short8 b, f32x4 c){
  return mfma_sel(a, b, c, 0);
}

// h-image layout: A-fragment-friendly permutation of [k=0..511][row=0..15] bf16.
// element (k,row) at index ((w*64 + g*16 + row)*4 + t4)*8 + e,
// w=k>>7, t4=(k>>5)&3, g=(k>>3)&3, e=k&7  -> consumer lane (g*16+row) loads one
// 16B dwordx4 per (w,t4) giving its 8 consecutive-k bf16 values.
__device__ __forceinline__ void img_store(u16* dst, int k, int row, int q){
  int w = k >> 7;
  int t4 = (k >> 5) & 3;
  int g  = (k >> 3) & 3;
  int e  = k & 7;
  dst[((w*64 + g*16 + row)*4 + t4)*8 + e] = f2bf((float)q);
}

// ---------------- phase 0: quantization / tables ----------------
__global__ void k0a_qx(const float* __restrict__ x, u16* __restrict__ qx, int n4){
  int i = blockIdx.x * blockDim.x + threadIdx.x;
  int st = gridDim.x * blockDim.x;
  for (; i < n4; i += st) {
    float4 v = ((const float4*)x)[i];
    ushort4 o;
    o.x = qbf(v.x, 16.f); o.y = qbf(v.y, 16.f);
    o.z = qbf(v.z, 16.f); o.w = qbf(v.w, 16.f);
    ((ushort4*)qx)[i] = o;
  }
}

__global__ void k0b_qwr(const float* __restrict__ W, const float* __restrict__ Rm,
                        u16* __restrict__ qwT, u16* __restrict__ qrT){
  int idx = blockIdx.x * 256 + threadIdx.x;       // 0 .. 2*786432-1
  if (idx >= 2*786432) return;
  int m = idx >= 786432;
  int rem = idx - m * 786432;                     // = k*1536 + n (coalesced read)
  int k = rem / 1536;
  int n = rem - k * 1536;
  const float* s = m ? Rm : W;
  u16* d = m ? qrT : qwT;
  d[n*512 + k] = qbf(s[rem], 1024.f);
}

__global__ void k0c_misc(const float* __restrict__ bx, const float* __restrict__ br,
                         int* __restrict__ qbx, int* __restrict__ qbr,
                         int* __restrict__ lut, int* __restrict__ flags){
  int i = blockIdx.x * 256 + threadIdx.x;
  if (i < 1536) {
    int qx_ = (int)rintf(bx[i] * 256.f);
    int qr_ = (int)rintf(br[i] * 256.f);
    qbx[i] = iclip8(qx_);
    qbr[i] = iclip8(qr_);
  }
  if (i < 256) {
    double v = (i - 128) * 0.125;               // all possible pre-activations
    float sg = (float)(1.0 / (1.0 + exp(-v)));
    int qs = (int)rintf(sg * 256.f);
    lut[i] = qs < 0 ? 0 : (qs > 255 ? 255 : qs);
    float th = (float)tanh(v);
    lut[256 + i] = iclip8((int)rintf(th * 128.f));
  }
  if (i < 2052) flags[i] = 0;
}

// ---------------- phase 1: Wx = fq(xq @ Wq, 4), stored int8 ----------------
// 128x128 tile, BK=64, 4 waves each a 64x64 quadrant of 4x4 16x16 tiles.
__global__ __launch_bounds__(256) void k1_gemm_wx(const u16* __restrict__ qx,
                                                  const u16* __restrict__ qwT,
                                                  i8* __restrict__ qwx){
  __shared__ u16 xs[128][72];
  __shared__ u16 ws[128][72];
  int bid = blockIdx.x;
  int n0 = (bid % 12) * 128;
  int m0 = (bid / 12) * 128;
  int tid = threadIdx.x;
  int lane = tid & 63, wid = tid >> 6;
  int wm = wid >> 1, wn = wid & 1;
  int g = lane >> 4, l15 = lane & 15;

  f32x4 acc[4][4] = {};
  for (int kc = 0; kc < 512; kc += 64) {
    __syncthreads();
#pragma unroll
    for (int p = 0; p < 4; p++) {
      int idx = p*256 + tid;           // 1024 dwordx4 slots per matrix
      int r = idx >> 3, c8 = idx & 7;
      *(uint4*)&xs[r][c8*8] = *(const uint4*)&qx [(size_t)(m0 + r)*512 + kc + c8*8];
      *(uint4*)&ws[r][c8*8] = *(const uint4*)&qwT[(size_t)(n0 + r)*512 + kc + c8*8];
    }
    __syncthreads();
#pragma unroll
    for (int kt = 0; kt < 2; kt++) {
      short8 a[4], b[4];
#pragma unroll
      for (int t = 0; t < 4; t++) {
        a[t] = *(const short8*)&xs[wm*64 + t*16 + l15][kt*32 + g*8];
        b[t] = *(const short8*)&ws[wn*64 + t*16 + l15][kt*32 + g*8];
      }
#pragma unroll
      for (int i = 0; i < 4; i++)
#pragma unroll
        for (int j = 0; j < 4; j++)
          acc[i][j] = mfma_bf16(a[i], b[j], acc[i][j]);
    }
  }
  // epilogue: fq(acc, 4) relative to scale 1/(16*1024): q = rhe(acc/1024)
#pragma unroll
  for (int i = 0; i < 4; i++)
#pragma unroll
    for (int j = 0; j < 4; j++)
#pragma unroll
      for (int r = 0; r < 4; r++) {
        float s = acc[i][j][r];
        float q = fminf(fmaxf(rintf(s * 0x1p-10f), -128.f), 127.f);
        int row = m0 + wm*64 + i*16 + g*4 + r;   // C/D: row = 4*(lane>>4)+reg
        int col = n0 + wn*64 + j*16 + l15;       //      col = lane&15
        qwx[(size_t)row * 1536 + col] = (i8)(int)q;
      }
}

// ---------------- phase 2: 512-step recurrence ----------------
// 64 WGs: bg in [0,4) owns 16 batch rows, cg in [0,16) owns 32 h-cols (96 Rh cols).
// R-slice lives in registers as B-fragments for all 512 steps. h exchanged via
// global ring images + per-step flag counters (device-scope release/acquire).
__global__ __launch_bounds__(256) void k2_gru(const float* __restrict__ h0,
                                              const i8*  __restrict__ qwx,
                                              const u16* __restrict__ qrT,
                                              const int* __restrict__ qbx,
                                              const int* __restrict__ qbr,
                                              const int* __restrict__ lut,
                                              u16* __restrict__ ring,
                                              int* __restrict__ flags,
                                              float* __restrict__ out){
  const int bid = blockIdx.x;
  const int bg  = (bid & 7) >> 1;                 // XCD-friendly heuristic mapping
  const int cg  = ((bid >> 3) << 1) | (bid & 1);
  const int tid = threadIdx.x;
  const int lane = tid & 63, wid = tid >> 6;      // wave = K-slice of 128
  const int g = lane >> 4, l15 = lane & 15;

  __shared__ float red[4][16][96];                // per-wave partial C
  __shared__ int   rhb[16][96];                   // quantized Rh+br
  __shared__ int   l_bx[96], l_br[96];
  __shared__ int   l_sig[256], l_th[256];

  if (tid < 256) { l_sig[tid] = lut[tid]; l_th[tid] = lut[256 + tid]; }
  if (tid < 96) {
    int gate = tid / 32, c = tid - gate*32;
    int colg = gate*512 + cg*32 + c;
    l_bx[tid] = qbx[colg];
    l_br[tid] = qbr[colg];
  }

  // ---- R fragments (B operand), resident in registers: 6 n-tiles x 4 k-tiles
  short8 rf[6][4];
#pragma unroll
  for (int n = 0; n < 6; n++) {
    int colg = (n >> 1)*512 + cg*32 + ((n & 1) << 4) + l15;   // B: col = lane&15
#pragma unroll
    for (int t4 = 0; t4 < 4; t4++)
      rf[n][t4] = *(const short8*)&qrT[(size_t)colg*512 + wid*128 + t4*32 + g*8];
  }

  // ---- own h state: 2 elements per thread (row = tid>>4, cols c0,c0+1)
  const int row = tid >> 4;
  const int c0  = (tid & 15) << 1;
  int qh0 = iclip8((int)rintf(h0[(size_t)(bg*16 + row)*512 + cg*32 + c0    ] * 128.f));
  int qh1 = iclip8((int)rintf(h0[(size_t)(bg*16 + row)*512 + cg*32 + c0 + 1] * 128.f));

  // publish h(0) image (slot 0)
  {
    u16* dst = ring + (size_t)(0*4 + bg) * 8192;
    img_store(dst, cg*32 + c0,     row, qh0);
    img_store(dst, cg*32 + c0 + 1, row, qh1);
  }
  __syncthreads();
  if (tid == 0) {
    __threadfence();
    __hip_atomic_fetch_add(&flags[0*4 + bg], 1, __ATOMIC_RELEASE, __HIP_MEMORY_SCOPE_AGENT);
  }

  for (int t = 0; t < NSTEP; t++) {
    // prefetch Wx for this step (independent of h, overlaps the flag wait)
    const i8* wxp = qwx + (size_t)t*(64*1536) + (size_t)(bg*16 + row)*1536 + cg*32;
    int wz0 = wxp[c0],        wz1 = wxp[c0 + 1];
    int wr0 = wxp[512 + c0],  wr1 = wxp[512 + c0 + 1];
    int wg0 = wxp[1024 + c0], wg1 = wxp[1024 + c0 + 1];

    // wait for h(t) from all 16 column-WGs of this batch group
    if (tid == 0) {
      int spins = 0;
      while (__hip_atomic_load(&flags[t*4 + bg], __ATOMIC_RELAXED,
                               __HIP_MEMORY_SCOPE_AGENT) < NCG) {
        __builtin_amdgcn_s_sleep(2);
        if (++spins > (1 << 26)) break;   // safety valve (never expected)
      }
    }
    __syncthreads();
    __threadfence();   // acquire: invalidate stale cache before image reads

    // A fragments of h(t)
    const u16* img = ring + (size_t)((t & 1)*4 + bg) * 8192;
    short8 af[4];
#pragma unroll
    for (int t4 = 0; t4 < 4; t4++)
      af[t4] = *(const short8*)&img[((wid*64 + lane)*4 + t4)*8];

    f32x4 acc[6] = {};
#pragma unroll
    for (int t4 = 0; t4 < 4; t4++)
#pragma unroll
      for (int n = 0; n < 6; n++)
        acc[n] = mfma_bf16(af[t4], rf[n][t4], acc[n]);

#pragma unroll
    for (int n = 0; n < 6; n++)
#pragma unroll
      for (int r = 0; r < 4; r++)
        red[wid][g*4 + r][n*16 + l15] = acc[n][r];
    __syncthreads();

    // reduce K-slices, then Rh -> Rh+br quantization (all exact integers)
#pragma unroll
    for (int ii = 0; ii < 6; ii++) {
      int lin = tid*6 + ii;                 // 0..1535 over [16][96]
      int rr2 = lin / 96, cc = lin - rr2*96;
      float S = red[0][rr2][cc] + red[1][rr2][cc] + red[2][rr2][cc] + red[3][rr2][cc];
      int qRh = iclip8((int)rintf(S * 0x1p-13f));       // fq(h@R, 4)
      rhb[rr2][cc] = iclip8(rhe(qRh*16 + l_br[cc], 4)); // fq(Rh+br, 4)
    }
    __syncthreads();

    // gates + state update for this thread's 2 elements
    u16* dst = ring + (size_t)(((t + 1) & 1)*4 + bg) * 8192;
    float* op = out + ((size_t)t*64 + bg*16 + row)*512 + cg*32;

    {
      int rz = rhb[row][c0], rr = rhb[row][32 + c0], rg = rhb[row][64 + c0];
      int uz = l_sig[128 + iclip8(rhe(16*(wz0 + rz) + l_bx[c0],      5))];
      int ur = l_sig[128 + iclip8(rhe(16*(wr0 + rr) + l_bx[32 + c0], 5))];
      int qrh = iclip8(rhe(ur * rg, 8));
      int qg  = l_th[128 + iclip8(rhe(16*(wg0 + qrh) + l_bx[64 + c0], 5))];
      int qold = iclip8(rhe(uz * qh0, 8));
      int qnew = iclip8(rhe((256 - uz) * qg, 8));
      qh0 = iclip8(qold + qnew);
      op[c0] = qh0 * 0.0078125f;
      img_store(dst, cg*32 + c0, row, qh0);
    }
    {
      int c1 = c0 + 1;
      int rz = rhb[row][c1], rr = rhb[row][32 + c1], rg = rhb[row][64 + c1];
      int uz = l_sig[128 + iclip8(rhe(16*(wz1 + rz) + l_bx[c1],      5))];
      int ur = l_sig[128 + iclip8(rhe(16*(wr1 + rr) + l_bx[32 + c1], 5))];
      int qrh = iclip8(rhe(ur * rg, 8));
      int qg  = l_th[128 + iclip8(rhe(16*(wg1 + qrh) + l_bx[64 + c1], 5))];
      int qold = iclip8(rhe(uz * qh1, 8));
      int qnew = iclip8(rhe((256 - uz) * qg, 8));
      qh1 = iclip8(qold + qnew);
      op[c1] = qh1 * 0.0078125f;
      img_store(dst, cg*32 + c1, row, qh1);
    }
    __syncthreads();
    if (tid == 0) {
      __threadfence();   // release: publish image + out stores
      __hip_atomic_fetch_add(&flags[(t + 1)*4 + bg], 1, __ATOMIC_RELEASE,
                             __HIP_MEMORY_SCOPE_AGENT);
    }
  }
}

// ---------------- launch ----------------
extern "C" void kernel_launch(void* const* d_in, const int* in_sizes, int n_in,
                              void* d_out, int out_size, void* d_ws, size_t ws_size,
                              hipStream_t stream) {
  const float* x  = (const float*)d_in[0];
  const float* h0 = (const float*)d_in[1];
  const float* W  = (const float*)d_in[2];
  const float* R  = (const float*)d_in[3];
  const float* bx = (const float*)d_in[4];
  const float* br = (const float*)d_in[5];
  float* out = (float*)d_out;

  if (ws_size < WS_NEED) return;   // insufficient scratch; fail loudly

  char* ws = (char*)d_ws;
  u16* qxbf  = (u16*)(ws + OFF_QXBF);
  u16* qwT   = (u16*)(ws + OFF_QWT);
  u16* qrT   = (u16*)(ws + OFF_QRT);
  i8*  qwx   = (i8*) (ws + OFF_QWX);
  int* qbx   = (int*)(ws + OFF_QBX);
  int* qbr   = (int*)(ws + OFF_QBR);
  int* lut   = (int*)(ws + OFF_LUT);
  u16* ring  = (u16*)(ws + OFF_RING);
  int* flags = (int*)(ws + OFF_FLAGS);

  k0a_qx  <<<2048, 256, 0, stream>>>(x, qxbf, 32768*512/4);
  k0b_qwr <<<6144, 256, 0, stream>>>(W, R, qwT, qrT);
  k0c_misc<<<16,   256, 0, stream>>>(bx, br, qbx, qbr, lut, flags);
  k1_gemm_wx<<<3072, 256, 0, stream>>>(qxbf, qwT, qwx);
  k2_gru  <<<64, 256, 0, stream>>>(h0, qwx, qrT, qbx, qbr, lut, ring, flags, out);
}

// Round 2
// 1347.868 us; speedup vs baseline: 3.5868x; 3.5868x over previous
//
#include <hip/hip_runtime.h>

typedef unsigned short u16;
typedef unsigned int   u32;
typedef signed char    i8;
typedef __attribute__((ext_vector_type(8))) short  short8;
typedef __attribute__((ext_vector_type(8))) __bf16 bf16x8;
typedef __attribute__((ext_vector_type(4))) float  f32x4;

// ---------------- problem constants ----------------
#define NSTEP 512
#define NBG 4
#define NCG 16

// ---------------- workspace layout (bytes) ----------------
#define OFF_QXBF  0ull
#define SZ_QXBF   (32768ull*512*2)          // x quantized, bf16(int)
#define OFF_QWT   (OFF_QXBF + SZ_QXBF)
#define SZ_QWT    (1536ull*512*2)           // W^T quantized, bf16(int)
#define OFF_QRT   (OFF_QWT + SZ_QWT)        // R^T quantized, bf16(int)
#define OFF_QWX   (OFF_QRT + SZ_QWT)
#define SZ_QWX    (32768ull*1536)           // Wx quantized, int8
#define OFF_QBX   (OFF_QWX + SZ_QWX)        // 1536 int
#define OFF_QBR   (OFF_QBX + 6144)          // 1536 int
#define OFF_LUT   (OFF_QBR + 6144)          // 256 int sigmoid + 256 int tanh
#define OFF_RING  (OFF_LUT + 2048)          // 2 slots x 4 bg x 4096 u32 tagged h-words
#define RING_WORDS (2*4*4096)
#define SZ_RING   (RING_WORDS*4ull)
#define WS_NEED   (OFF_RING + SZ_RING)

// ---------------- helpers ----------------
__device__ __forceinline__ int iclip8(int v){ return v < -128 ? -128 : (v > 127 ? 127 : v); }

// round-half-even of (v / 2^k) for integer v (matches rintf/jnp.round on exact values)
__device__ __forceinline__ int rhe(int v, int k){
  int b = v >> k;                 // floor
  int r = v & ((1 << k) - 1);
  int half = 1 << (k - 1);
  return b + ((r > half) || (r == half && (b & 1)));
}

__device__ __forceinline__ u16 f2bf(float f){ return (u16)(__builtin_bit_cast(u32, f) >> 16); }

// quantize x*s to [-128,127], return exact bf16 of the (integer) result
__device__ __forceinline__ u16 qbf(float x, float s){
  float q = rintf(x * s);
  q = fminf(fmaxf(q, -128.f), 127.f);
  return f2bf(q);   // integers |q|<=128 are exact in bf16
}

__device__ __forceinline__ short bf_of_i8(u32 x){
  int v = (int)(signed char)(x & 0xFF);
  return (short)f2bf((float)v);
}

// MFMA wrapper: tolerate either short8- or bf16x8-typed builtin signature.
template<typename V>
__device__ __forceinline__ auto mfma_sel(V a, V b, f32x4 c, int)
  -> decltype(__builtin_amdgcn_mfma_f32_16x16x32_bf16(a, b, c, 0, 0, 0)) {
  return __builtin_amdgcn_mfma_f32_16x16x32_bf16(a, b, c, 0, 0, 0);
}
template<typename V>
__device__ __forceinline__ f32x4 mfma_sel(V a, V b, f32x4 c, long) {
  return __builtin_amdgcn_mfma_f32_16x16x32_bf16(
      __builtin_bit_cast(bf16x8, a), __builtin_bit_cast(bf16x8, b), c, 0, 0, 0);
}
__device__ __forceinline__ f32x4 mfma_bf16(short8 a, short8 b, f32x4 c){
  return mfma_sel(a, b, c, 0);
}

// tagged h-image: word index for (k, row), word = h(k)|h(k+1)<<8|tag<<16 (k even).
// w=k>>7 (consumer wave), t4=(k>>5)&3, g=(k>>3)&3, pair=(k&7)>>1
// consumer lane (g*16+row) of wave w loads one dwordx4 per t4 (4 tagged words).
__device__ __forceinline__ int img_widx(int k, int row){
  int w = k >> 7;
  int t4 = (k >> 5) & 3;
  int g  = (k >> 3) & 3;
  int pr = (k & 7) >> 1;
  return ((w*64 + g*16 + row)*4 + t4)*4 + pr;
}

// coherent (LLC, bypass L1/L2) store of one tagged word — no fence needed
__device__ __forceinline__ void llc_store(u32* p, u32 word){
  unsigned long long a = (unsigned long long)p;
  asm volatile("global_store_dword %0, %1, off sc0 sc1" :: "v"(a), "v"(word) : "memory");
}

// ---------------- phase 0: quantization / tables ----------------
__global__ void k0a_qx(const float* __restrict__ x, u16* __restrict__ qx, int n4){
  int i = blockIdx.x * blockDim.x + threadIdx.x;
  int st = gridDim.x * blockDim.x;
  for (; i < n4; i += st) {
    float4 v = ((const float4*)x)[i];
    ushort4 o;
    o.x = qbf(v.x, 16.f); o.y = qbf(v.y, 16.f);
    o.z = qbf(v.z, 16.f); o.w = qbf(v.w, 16.f);
    ((ushort4*)qx)[i] = o;
  }
}

__global__ void k0b_qwr(const float* __restrict__ W, const float* __restrict__ Rm,
                        u16* __restrict__ qwT, u16* __restrict__ qrT){
  int idx = blockIdx.x * 256 + threadIdx.x;       // 0 .. 2*786432-1
  if (idx >= 2*786432) return;
  int m = idx >= 786432;
  int rem = idx - m * 786432;                     // = k*1536 + n (coalesced read)
  int k = rem / 1536;
  int n = rem - k * 1536;
  const float* s = m ? Rm : W;
  u16* d = m ? qrT : qwT;
  d[n*512 + k] = qbf(s[rem], 1024.f);
}

__global__ void k0c_misc(const float* __restrict__ bx, const float* __restrict__ br,
                         int* __restrict__ qbx, int* __restrict__ qbr,
                         int* __restrict__ lut, u32* __restrict__ ring){
  int i = blockIdx.x * 256 + threadIdx.x;         // 4096 threads
  if (i < 1536) {
    int qx_ = (int)rintf(bx[i] * 256.f);
    int qr_ = (int)rintf(br[i] * 256.f);
    qbx[i] = iclip8(qx_);
    qbr[i] = iclip8(qr_);
  }
  if (i < 256) {
    double v = (i - 128) * 0.125;               // all possible pre-activations
    float sg = (float)(1.0 / (1.0 + exp(-v)));
    int qs = (int)rintf(sg * 256.f);
    lut[i] = qs < 0 ? 0 : (qs > 255 ? 255 : qs);
    float th = (float)tanh(v);
    lut[256 + i] = iclip8((int)rintf(th * 128.f));
  }
  // zero the ring EVERY launch: tags are >=1, so no garbage/leftover can match
#pragma unroll
  for (int r = 0; r < RING_WORDS/4096; r++)
    ring[r*4096 + i] = 0u;
}

// ---------------- phase 1: Wx = fq(xq @ Wq, 4), stored int8 ----------------
// 128x128 tile, BK=64, 4 waves each a 64x64 quadrant of 4x4 16x16 tiles.
__global__ __launch_bounds__(256) void k1_gemm_wx(const u16* __restrict__ qx,
                                                  const u16* __restrict__ qwT,
                                                  i8* __restrict__ qwx){
  __shared__ u16 xs[128][72];
  __shared__ u16 ws[128][72];
  int bid = blockIdx.x;
  int n0 = (bid % 12) * 128;
  int m0 = (bid / 12) * 128;
  int tid = threadIdx.x;
  int lane = tid & 63, wid = tid >> 6;
  int wm = wid >> 1, wn = wid & 1;
  int g = lane >> 4, l15 = lane & 15;

  f32x4 acc[4][4] = {};
  for (int kc = 0; kc < 512; kc += 64) {
    __syncthreads();
#pragma unroll
    for (int p = 0; p < 4; p++) {
      int idx = p*256 + tid;           // 1024 dwordx4 slots per matrix
      int r = idx >> 3, c8 = idx & 7;
      *(uint4*)&xs[r][c8*8] = *(const uint4*)&qx [(size_t)(m0 + r)*512 + kc + c8*8];
      *(uint4*)&ws[r][c8*8] = *(const uint4*)&qwT[(size_t)(n0 + r)*512 + kc + c8*8];
    }
    __syncthreads();
#pragma unroll
    for (int kt = 0; kt < 2; kt++) {
      short8 a[4], b[4];
#pragma unroll
      for (int t = 0; t < 4; t++) {
        a[t] = *(const short8*)&xs[wm*64 + t*16 + l15][kt*32 + g*8];
        b[t] = *(const short8*)&ws[wn*64 + t*16 + l15][kt*32 + g*8];
      }
#pragma unroll
      for (int i = 0; i < 4; i++)
#pragma unroll
        for (int j = 0; j < 4; j++)
          acc[i][j] = mfma_bf16(a[i], b[j], acc[i][j]);
    }
  }
  // epilogue: fq(acc, 4) relative to scale 1/(16*1024): q = rhe(acc/1024)
#pragma unroll
  for (int i = 0; i < 4; i++)
#pragma unroll
    for (int j = 0; j < 4; j++)
#pragma unroll
      for (int r = 0; r < 4; r++) {
        float s = acc[i][j][r];
        float q = fminf(fmaxf(rintf(s * 0x1p-10f), -128.f), 127.f);
        int row = m0 + wm*64 + i*16 + g*4 + r;   // C/D: row = 4*(lane>>4)+reg
        int col = n0 + wn*64 + j*16 + l15;       //      col = lane&15
        qwx[(size_t)row * 1536 + col] = (i8)(int)q;
      }
}

// ---------------- phase 2: 512-step recurrence ----------------
// 64 WGs: bg owns 16 batch rows, cg owns 32 h-cols (96 Rh cols). R-slice lives
// in registers as B-fragments for all 512 steps. h exchanged via LLC-coherent
// tagged words: no fences, no atomics, no flags — consumers poll data tags.
__global__ __launch_bounds__(256) void k2_gru(const float* __restrict__ h0,
                                              const i8*  __restrict__ qwx,
                                              const u16* __restrict__ qrT,
                                              const int* __restrict__ qbx,
                                              const int* __restrict__ qbr,
                                              const int* __restrict__ lut,
                                              u32* __restrict__ ring,
                                              float* __restrict__ out){
  const int bid = blockIdx.x;
  const int bg  = (bid & 7) >> 1;                 // spread bg across XCDs
  const int cg  = ((bid >> 3) << 1) | (bid & 1);
  const int tid = threadIdx.x;
  const int lane = tid & 63, wid = tid >> 6;      // wave = K-slice of 128
  const int g = lane >> 4, l15 = lane & 15;

  __shared__ float red[4][16][97];                // padded: kill bank conflicts
  __shared__ int   rhb[16][96];                   // quantized Rh+br
  __shared__ int   l_bx[96], l_br[96];
  __shared__ int   l_sig[256], l_th[256];

  if (tid < 256) { l_sig[tid] = lut[tid]; l_th[tid] = lut[256 + tid]; }
  if (tid < 96) {
    int gate = tid / 32, c = tid - gate*32;
    int colg = gate*512 + cg*32 + c;
    l_bx[tid] = qbx[colg];
    l_br[tid] = qbr[colg];
  }

  // ---- R fragments (B operand), resident in registers: 6 n-tiles x 4 k-tiles
  short8 rf[6][4];
#pragma unroll
  for (int n = 0; n < 6; n++) {
    int colg = (n >> 1)*512 + cg*32 + ((n & 1) << 4) + l15;   // B: col = lane&15
#pragma unroll
    for (int t4 = 0; t4 < 4; t4++)
      rf[n][t4] = *(const short8*)&qrT[(size_t)colg*512 + wid*128 + t4*32 + g*8];
  }

  // ---- own h state: 2 elements per thread (row = tid>>4, cols c0,c0+1)
  const int row = tid >> 4;
  const int c0  = (tid & 15) << 1;
  int qh0 = iclip8((int)rintf(h0[(size_t)(bg*16 + row)*512 + cg*32 + c0    ] * 128.f));
  int qh1 = iclip8((int)rintf(h0[(size_t)(bg*16 + row)*512 + cg*32 + c0 + 1] * 128.f));

  // publish h(0): slot 0, tag 1  (tag of h(T) = T+1, never 0)
  {
    u32* dst = ring + (size_t)(0*4 + bg) * 4096;
    u32 word = (u32)(qh0 & 0xFF) | ((u32)(qh1 & 0xFF) << 8) | (1u << 16);
    llc_store(&dst[img_widx(cg*32 + c0, row)], word);
  }
  __syncthreads();

  const unsigned long long pollbase0 =
      (unsigned long long)ring + (unsigned long long)((wid*64 + lane)*4) * 16ull;

  for (int t = 0; t < NSTEP; t++) {
    // prefetch Wx for this step (plain cached loads; independent of h)
    const i8* wxp = qwx + (size_t)t*(64*1536) + (size_t)(bg*16 + row)*1536 + cg*32;
    int wz0 = wxp[c0],        wz1 = wxp[c0 + 1];
    int wr0 = wxp[512 + c0],  wr1 = wxp[512 + c0 + 1];
    int wg0 = wxp[1024 + c0], wg1 = wxp[1024 + c0 + 1];

    // ---- poll the 16 tagged words this lane needs (h(t), slot t&1, tag t+1)
    const u32 want = (u32)(t + 1);
    unsigned long long pb = pollbase0 + (unsigned long long)(((t & 1)*4 + bg)*4096) * 4ull;
    uint4 v0, v1, v2, v3;
    bool ok;
    do {
      asm volatile(
        "global_load_dwordx4 %0, %4, off sc0 sc1\n\t"
        "global_load_dwordx4 %1, %4, off offset:16 sc0 sc1\n\t"
        "global_load_dwordx4 %2, %4, off offset:32 sc0 sc1\n\t"
        "global_load_dwordx4 %3, %4, off offset:48 sc0 sc1\n\t"
        "s_waitcnt vmcnt(0)"
        : "=&v"(v0), "=&v"(v1), "=&v"(v2), "=&v"(v3)
        : "v"(pb)
        : "memory");
      u32 m;
      m  = (v0.x >> 16) ^ want; m |= (v0.y >> 16) ^ want;
      m |= (v0.z >> 16) ^ want; m |= (v0.w >> 16) ^ want;
      m |= (v1.x >> 16) ^ want; m |= (v1.y >> 16) ^ want;
      m |= (v1.z >> 16) ^ want; m |= (v1.w >> 16) ^ want;
      m |= (v2.x >> 16) ^ want; m |= (v2.y >> 16) ^ want;
      m |= (v2.z >> 16) ^ want; m |= (v2.w >> 16) ^ want;
      m |= (v3.x >> 16) ^ want; m |= (v3.y >> 16) ^ want;
      m |= (v3.z >> 16) ^ want; m |= (v3.w >> 16) ^ want;
      ok = (m == 0);
      if (!ok) __builtin_amdgcn_s_sleep(1);
    } while (!ok);

    // ---- unpack tagged int8 pairs -> bf16 A fragments
    short8 af[4];
    {
      uint4 wv[4] = {v0, v1, v2, v3};
#pragma unroll
      for (int t4 = 0; t4 < 4; t4++) {
        uint4 w = wv[t4];
        short8 f;
        f[0] = bf_of_i8(w.x); f[1] = bf_of_i8(w.x >> 8);
        f[2] = bf_of_i8(w.y); f[3] = bf_of_i8(w.y >> 8);
        f[4] = bf_of_i8(w.z); f[5] = bf_of_i8(w.z >> 8);
        f[6] = bf_of_i8(w.w); f[7] = bf_of_i8(w.w >> 8);
        af[t4] = f;
      }
    }

    f32x4 acc[6] = {};
#pragma unroll
    for (int t4 = 0; t4 < 4; t4++)
#pragma unroll
      for (int n = 0; n < 6; n++)
        acc[n] = mfma_bf16(af[t4], rf[n][t4], acc[n]);

#pragma unroll
    for (int n = 0; n < 6; n++)
#pragma unroll
      for (int r = 0; r < 4; r++)
        red[wid][g*4 + r][n*16 + l15] = acc[n][r];
    __syncthreads();

    // reduce K-slices, then Rh -> Rh+br quantization (all exact integers)
#pragma unroll
    for (int ii = 0; ii < 6; ii++) {
      int lin = tid*6 + ii;                 // 0..1535 over [16][96]
      int rr2 = lin / 96, cc = lin - rr2*96;
      float S = red[0][rr2][cc] + red[1][rr2][cc] + red[2][rr2][cc] + red[3][rr2][cc];
      int qRh = iclip8((int)rintf(S * 0x1p-13f));       // fq(h@R, 4)
      rhb[rr2][cc] = iclip8(rhe(qRh*16 + l_br[cc], 4)); // fq(Rh+br, 4)
    }
    __syncthreads();

    // gates + state update for this thread's 2 elements
    u32* dst = ring + (size_t)(((t + 1) & 1)*4 + bg) * 4096;
    float* op = out + ((size_t)t*64 + bg*16 + row)*512 + cg*32;

    {
      int rz = rhb[row][c0], rr = rhb[row][32 + c0], rg = rhb[row][64 + c0];
      int uz = l_sig[128 + iclip8(rhe(16*(wz0 + rz) + l_bx[c0],      5))];
      int ur = l_sig[128 + iclip8(rhe(16*(wr0 + rr) + l_bx[32 + c0], 5))];
      int qrh = iclip8(rhe(ur * rg, 8));
      int qg  = l_th[128 + iclip8(rhe(16*(wg0 + qrh) + l_bx[64 + c0], 5))];
      int qold = iclip8(rhe(uz * qh0, 8));
      int qnew = iclip8(rhe((256 - uz) * qg, 8));
      qh0 = iclip8(qold + qnew);
    }
    {
      int c1 = c0 + 1;
      int rz = rhb[row][c1], rr = rhb[row][32 + c1], rg = rhb[row][64 + c1];
      int uz = l_sig[128 + iclip8(rhe(16*(wz1 + rz) + l_bx[c1],      5))];
      int ur = l_sig[128 + iclip8(rhe(16*(wr1 + rr) + l_bx[32 + c1], 5))];
      int qrh = iclip8(rhe(ur * rg, 8));
      int qg  = l_th[128 + iclip8(rhe(16*(wg1 + qrh) + l_bx[64 + c1], 5))];
      int qold = iclip8(rhe(uz * qh1, 8));
      int qnew = iclip8(rhe((256 - uz) * qg, 8));
      qh1 = iclip8(qold + qnew);
    }
    // publish h(t+1) FIRST (earliest cross-WG visibility), then out
    {
      u32 word = (u32)(qh0 & 0xFF) | ((u32)(qh1 & 0xFF) << 8) | ((u32)(t + 2) << 16);
      llc_store(&dst[img_widx(cg*32 + c0, row)], word);
    }
    op[c0]     = qh0 * 0.0078125f;
    op[c0 + 1] = qh1 * 0.0078125f;
    __syncthreads();   // protect red[]/rhb[] reuse next step
  }
}

// ---------------- launch ----------------
extern "C" void kernel_launch(void* const* d_in, const int* in_sizes, int n_in,
                              void* d_out, int out_size, void* d_ws, size_t ws_size,
                              hipStream_t stream) {
  const float* x  = (const float*)d_in[0];
  const float* h0 = (const float*)d_in[1];
  const float* W  = (const float*)d_in[2];
  const float* R  = (const float*)d_in[3];
  const float* bx = (const float*)d_in[4];
  const float* br = (const float*)d_in[5];
  float* out = (float*)d_out;

  if (ws_size < WS_NEED) return;   // insufficient scratch; fail loudly

  char* ws = (char*)d_ws;
  u16* qxbf  = (u16*)(ws + OFF_QXBF);
  u16* qwT   = (u16*)(ws + OFF_QWT);
  u16* qrT   = (u16*)(ws + OFF_QRT);
  i8*  qwx   = (i8*) (ws + OFF_QWX);
  int* qbx   = (int*)(ws + OFF_QBX);
  int* qbr   = (int*)(ws + OFF_QBR);
  int* lut   = (int*)(ws + OFF_LUT);
  u32* ring  = (u32*)(ws + OFF_RING);

  k0a_qx  <<<2048, 256, 0, stream>>>(x, qxbf, 32768*512/4);
  k0b_qwr <<<6144, 256, 0, stream>>>(W, R, qwT, qrT);
  k0c_misc<<<16,   256, 0, stream>>>(bx, br, qbx, qbr, lut, ring);
  k1_gemm_wx<<<3072, 256, 0, stream>>>(qxbf, qwT, qwx);
  k2_gru  <<<64, 256, 0, stream>>>(h0, qwx, qrT, qbx, qbr, lut, ring, out);
}